// Round 5
// baseline (75923.419 us; speedup 1.0000x reference)
//
#include <hip/hip_runtime.h>

#define NTHR 512
#define NBLK 256

// problem dims
#define B_    256
#define TE_   300
#define T_    600
#define NIN_  128
#define H_    512
#define EMB_  32
#define KE0_  160
#define KD0_  136            // 133 padded to 136 (zeros) for float4-aligned tiles
#define OUT_HE_OFS 768000ull // 256*600*5

// LDS tile sizes (floats)
#define ACT_F (32 * 68)
#define W_F   (48 * 68)

// ---- workspace layout (float offsets) ----
constexpr size_t OF_BAR  = 0;                       // 1024 floats (per-bi barriers)
constexpr size_t OF_XEMB = 1024;                    // 256*32
constexpr size_t OF_HA   = OF_XEMB + 8192;          // 2 * 256*512
constexpr size_t OF_HB   = OF_HA + 262144;          // 2 * 256*512
constexpr size_t OF_PV   = OF_HB + 262144;          // 256*8
constexpr size_t OF_S1   = OF_PV + 2048;            // 256*128 relu(fc1)
constexpr size_t OF_S2   = OF_S1 + 32768;           // 256*128 relu(he1)
constexpr size_t OF_E0I  = OF_S2 + 32768;           // 32*48*160
constexpr size_t OF_E0H  = OF_E0I + 245760;         // 32*48*512
constexpr size_t OF_E1I  = OF_E0H + 786432;
constexpr size_t OF_E1H  = OF_E1I + 786432;
constexpr size_t OF_D0I  = OF_E1H + 786432;         // 32*48*136
constexpr size_t OF_D0H  = OF_D0I + 208896;
constexpr size_t OF_D1I  = OF_D0H + 786432;
constexpr size_t OF_D1H  = OF_D1I + 786432;
constexpr size_t OF_FH   = OF_D1H + 786432;         // 32*8*512 (fc1+he1, c-major)
constexpr size_t WS_END  = OF_FH + 131072;          // ~23.6 MB total

// ---------------- init: zero barrier, build xemb, pv state, zero h slot-1 ----------------
__global__ void k_init(float* __restrict__ ws, const float* __restrict__ pv_init,
                       const int* __restrict__ scen, const float* __restrict__ emb) {
  const size_t total = 1024 + 8192 + 2048 + 131072 + 131072;
  size_t stride = (size_t)gridDim.x * blockDim.x;
  for (size_t x = (size_t)blockIdx.x * blockDim.x + threadIdx.x; x < total; x += stride) {
    if (x < 1024) {
      ((unsigned*)ws)[x] = 0u;
    } else if (x < 1024 + 8192) {
      size_t r = x - 1024; int b = (int)(r >> 5), e = (int)(r & 31);
      ws[OF_XEMB + r] = emb[scen[b] * EMB_ + e];
    } else if (x < 1024 + 8192 + 2048) {
      size_t r = x - 1024 - 8192; int b = (int)(r >> 3), p = (int)(r & 7);
      ws[OF_PV + r] = (p < 5) ? pv_init[b * 5 + p] : 0.f;
    } else if (x < 1024 + 8192 + 2048 + 131072) {
      ws[OF_HA + 131072 + (x - 1024 - 8192 - 2048)] = 0.f;        // hA slot 1 = zeros
    } else {
      ws[OF_HB + 131072 + (x - 1024 - 8192 - 2048 - 131072)] = 0.f; // hB slot 1 = zeros
    }
  }
}

// ---------------- weight rearrange: dst[g][c][Kp], c = gate*16 + hid_local ----------------
// c-major rows of padded length Kp (zeros for k>=K) so LDS staging/readers use float4.
__global__ void k_rearr(float* __restrict__ dst, const float* __restrict__ src, int K, int Kp) {
  int n = 32 * 48 * Kp;
  for (int idx = blockIdx.x * blockDim.x + threadIdx.x; idx < n; idx += gridDim.x * blockDim.x) {
    int g = idx / (48 * Kp), r = idx % (48 * Kp), c = r / Kp, k = r % Kp;
    int j = (c >> 4) * 512 + g * 16 + (c & 15);
    dst[idx] = (k < K) ? src[j * K + k] : 0.f;
  }
}
// fc1/he1 combined, c-major: dst[g][c][512] (c<4: fc1 col g*4+c; c>=4: he1 col g*4+c-4)
__global__ void k_rearr_fh(float* __restrict__ dst, const float* __restrict__ fc1,
                           const float* __restrict__ he1) {
  int n = 32 * 8 * 512;
  for (int idx = blockIdx.x * blockDim.x + threadIdx.x; idx < n; idx += gridDim.x * blockDim.x) {
    int g = idx / (8 * 512), r = idx % (8 * 512), c = r / 512, k = r % 512;
    const float* s = (c < 4) ? fc1 : he1;
    dst[idx] = s[(g * 4 + (c & 3)) * 512 + k];
  }
}

// ---------------- device helpers ----------------
__device__ __forceinline__ float sigm(float x) { return 1.f / (1.f + __expf(-x)); }
__device__ __forceinline__ float tanhx(float x) { float e = __expf(2.f * x); return 1.f - 2.f / (e + 1.f); }

// per-bi-group barrier: 32 WGs sharing batch rows sync; groups are independent
// (hA/hB/s1g/s2g/pv are row-partitioned; weights read-only).
__device__ __forceinline__ void bar_sync_bi(unsigned* bar, int big) {
  __syncthreads();
  if (threadIdx.x == 0) {
    unsigned* cnt = &bar[big << 6];
    unsigned* gen = &bar[(big << 6) + 16];
    unsigned g0 = __hip_atomic_load(gen, __ATOMIC_RELAXED, __HIP_MEMORY_SCOPE_AGENT);
    unsigned n = __hip_atomic_fetch_add(cnt, 1u, __ATOMIC_ACQ_REL, __HIP_MEMORY_SCOPE_AGENT);
    if (n == 31u) {
      __hip_atomic_store(cnt, 0u, __ATOMIC_RELAXED, __HIP_MEMORY_SCOPE_AGENT);
      __hip_atomic_store(gen, g0 + 1u, __ATOMIC_RELEASE, __HIP_MEMORY_SCOPE_AGENT);
    } else {
      while (__hip_atomic_load(gen, __ATOMIC_ACQUIRE, __HIP_MEMORY_SCOPE_AGENT) == g0)
        __builtin_amdgcn_s_sleep(1);
    }
  }
  __syncthreads();
}

#define FMA4(ACC, AV, WV)                                   \
  ACC = fmaf(AV.x, WV.x, ACC); ACC = fmaf(AV.y, WV.y, ACC); \
  ACC = fmaf(AV.z, WV.z, ACC); ACC = fmaf(AV.w, WV.w, ACC);

// one 4-k chunk, 4 rows: 7 ds_read_b128 -> 48 FMAs (4 rows x 3 gates x 4 k)
#define GQ4(Q, AX)                                                                   \
  { const int q_ = (Q);                                                              \
    const float4 wr = W4c[hc * 17 + q_];                                             \
    const float4 wz = W4c[(16 + hc) * 17 + q_];                                      \
    const float4 wn = W4c[(32 + hc) * 17 + q_];                                      \
    const float4 a0 = A4c[(rb + 0) * 17 + q_];                                       \
    const float4 a1 = A4c[(rb + 1) * 17 + q_];                                       \
    const float4 a2 = A4c[(rb + 2) * 17 + q_];                                       \
    const float4 a3 = A4c[(rb + 3) * 17 + q_];                                       \
    FMA4(aR[0], a0, wr) FMA4(aR[1], a1, wr) FMA4(aR[2], a2, wr) FMA4(aR[3], a3, wr)  \
    FMA4(aZ[0], a0, wz) FMA4(aZ[1], a1, wz) FMA4(aZ[2], a2, wz) FMA4(aZ[3], a3, wz)  \
    FMA4(AX[0], a0, wn) FMA4(AX[1], a1, wn) FMA4(AX[2], a2, wn) FMA4(AX[3], a3, wn)  \
  }

// register prefetch of one 64-k tile's operands (global -> VGPR)
template <int KIND, int KI>
__device__ __forceinline__ void stage_pref(
    int kt, int tid, int b0, int g, int t,
    const float* __restrict__ actA, const float* __restrict__ actB,
    const float* __restrict__ wi, const float* __restrict__ wh,
    const float* __restrict__ hprev,
    float4& wv0, float4& wv1, float4& av, bool& w0v, bool& w1v, bool& a_v) {
  constexpr int NTI = (KI + 63) >> 6;
  w0v = false; w1v = false; a_v = false;
  if (kt < NTI) {
    const int k0 = kt << 6;
    const int cnt = (KI - k0 >= 64) ? 64 : (KI - k0);
    const int L = (cnt == 64) ? 4 : (cnt == 32) ? 3 : 1;
    const int M = (1 << L) - 1;
    if (tid < (48 << L)) {
      w0v = true;
      const int c0 = tid >> L, f0 = tid & M;
      wv0 = *(const float4*)(wi + (size_t)(g * 48 + c0) * KI + k0 + (f0 << 2));
    }
    const int i1 = tid + 512;
    if (i1 < (48 << L)) {
      w1v = true;
      const int c1 = i1 >> L, f1 = i1 & M;
      wv1 = *(const float4*)(wi + (size_t)(g * 48 + c1) * KI + k0 + (f1 << 2));
    }
    if (tid < (32 << L)) {
      const int row = tid >> L, f = tid & M;
      if (KIND == 1) {
        av = *(const float4*)(actA + (size_t)(b0 + row) * H_ + k0 + (f << 2)); a_v = true;
      } else if (KIND == 0) {
        if (k0 < 128) {
          av = *(const float4*)(actA + ((size_t)(b0 + row) * TE_ + t) * NIN_ + k0 + (f << 2)); a_v = true;
        } else {
          av = *(const float4*)(actB + (size_t)(b0 + row) * EMB_ + (f << 2)); a_v = true;
        }
      } else {
        if (k0 < 128) {
          av = *(const float4*)(actA + ((size_t)(b0 + row) * T_ + t) * NIN_ + k0 + (f << 2)); a_v = true;
        } // pv tail filled from s_pvl at store time
      }
    }
  } else {
    const int k0 = (kt - NTI) << 6;
    w0v = true;
    wv0 = *(const float4*)(wh + (size_t)(g * 48 + (tid >> 4)) * 512 + k0 + ((tid & 15) << 2));
    if (tid < 256) {
      w1v = true;
      wv1 = *(const float4*)(wh + (size_t)(g * 48 + 32 + (tid >> 4)) * 512 + k0 + ((tid & 15) << 2));
    }
    av = *(const float4*)(hprev + (size_t)(b0 + (tid >> 4)) * H_ + k0 + ((tid & 15) << 2));
    a_v = true;
  }
}

// regs -> LDS for tile kt into the given half of the double buffer
template <int KIND, int KI>
__device__ __forceinline__ void stage_write(
    int kt, int tid, float* __restrict__ s_act_b, float* __restrict__ s_w_b,
    const float4& wv0, const float4& wv1, const float4& av,
    bool w0v, bool w1v, bool a_v, const float* __restrict__ s_pvl) {
  constexpr int NTI = (KI + 63) >> 6;
  const bool is_input = (kt < NTI);
  const int k0i = kt << 6;
  const int cnt = is_input ? ((KI - k0i >= 64) ? 64 : (KI - k0i)) : 64;
  const int L = (cnt == 64) ? 4 : (cnt == 32) ? 3 : 1;
  const int M = (1 << L) - 1;
  float4* W4 = (float4*)s_w_b;
  float4* A4 = (float4*)s_act_b;
  if (w0v) W4[(tid >> L) * 17 + (tid & M)] = wv0;
  if (w1v) { const int i1 = tid + 512; W4[(i1 >> L) * 17 + (i1 & M)] = wv1; }
  if (a_v) A4[(tid >> L) * 17 + (tid & M)] = av;
  if (KIND == 2 && is_input && k0i == 128 && tid < 64) {
    const int row = tid >> 1, f = tid & 1;
    float4 v;
    if (f == 0) {
      v.x = s_pvl[(row << 3) + 0]; v.y = s_pvl[(row << 3) + 1];
      v.z = s_pvl[(row << 3) + 2]; v.w = s_pvl[(row << 3) + 3];
    } else {
      v.x = s_pvl[(row << 3) + 4]; v.y = 0.f; v.z = 0.f; v.w = 0.f;
    }
    A4[row * 17 + f] = v;
  }
}

// One GRU step for this WG's tile: 32 batch rows x 16 hidden cols.
// Thread = (hc: lane bits 0-3, ks: lane bits 4-5 k-split quarter, wave = row-quad).
// Per thread: 4 rows x 16 k. Split-k reduced by in-wave butterfly shuffle (no LDS).
// LDS: act[row][68], w[gatecol][68], double-buffered -> ONE sync per 64-k tile.
// KIND 0: enc L0 (x_cv ++ xemb), 1: plain H input, 2: dec L0 (x_tgt ++ pv from s_pvl)
template <int KIND, int KI>
__device__ void gru_tile(const float* __restrict__ actA, const float* __restrict__ actB, int t,
                         const float* __restrict__ wi, const float* __restrict__ wh,
                         const float* __restrict__ bi, const float* __restrict__ bh,
                         const float* __restrict__ hprev, float* __restrict__ hout,
                         int b0, int g, float* __restrict__ s_act, float* __restrict__ s_w,
                         float* __restrict__ s_sb, const float* __restrict__ s_pvl) {
  const int tid = threadIdx.x;
  const int hc = tid & 15;            // hidden col 0..15 (lane bits 0-3)
  const int ks = (tid >> 4) & 3;      // k-split quarter 0..3 (lane bits 4-5)
  const int rq = tid >> 6;            // wave id = row quad 0..7
  const int rb = rq << 2;             // first of this wave's 4 rows
  float aR[4] = {0.f,0.f,0.f,0.f}, aZ[4] = {0.f,0.f,0.f,0.f};
  float aX[4] = {0.f,0.f,0.f,0.f}, aN[4] = {0.f,0.f,0.f,0.f};
  constexpr int NTI = (KI + 63) >> 6;
  constexpr int NTT = NTI + 8;

  float4 wv0 = {0,0,0,0}, wv1 = {0,0,0,0}, av = {0,0,0,0};
  bool w0v = false, w1v = false, a_v = false;
  // prologue: tile 0 -> buf0 (prior phase's LDS reads are behind its trailing sync)
  stage_pref<KIND, KI>(0, tid, b0, g, t, actA, actB, wi, wh, hprev, wv0, wv1, av, w0v, w1v, a_v);
  stage_write<KIND, KI>(0, tid, s_act, s_w, wv0, wv1, av, w0v, w1v, a_v, s_pvl);

  for (int kt = 0; kt < NTT; ++kt) {
    const bool is_input = (kt < NTI);
    const int k0i = kt << 6;
    const int cnt = is_input ? ((KI - k0i >= 64) ? 64 : (KI - k0i)) : 64;
    const int cur = kt & 1;

    __syncthreads();   // tile kt's writes visible; buf[cur^1] readers (tile kt-1) done
    if (kt + 1 < NTT)
      stage_pref<KIND, KI>(kt + 1, tid, b0, g, t, actA, actB, wi, wh, hprev, wv0, wv1, av, w0v, w1v, a_v);

    const float4* A4c = (const float4*)(s_act + cur * ACT_F);
    const float4* W4c = (const float4*)(s_w + cur * W_F);
    if (is_input) {
      if (cnt == 64) {
        const int qb = ks << 2;
#pragma unroll 2
        for (int ch = 0; ch < 4; ++ch) GQ4(qb + ch, aX)
      } else if (cnt == 32) {
        const int qb = ks << 1;
#pragma unroll 2
        for (int ch = 0; ch < 2; ++ch) GQ4(qb + ch, aX)
      } else { // cnt == 8: 2 chunks, ks 0/1 only
        if (ks < 2) GQ4(ks, aX)
      }
    } else {
      const int qb = ks << 2;
#pragma unroll 2
      for (int ch = 0; ch < 4; ++ch) GQ4(qb + ch, aN)
    }

    if (kt + 1 < NTT)
      stage_write<KIND, KI>(kt + 1, tid, s_act + (cur ^ 1) * ACT_F, s_w + (cur ^ 1) * W_F,
                            wv0, wv1, av, w0v, w1v, a_v, s_pvl);
  }

  __syncthreads();   // all compute reads done before next phase's prologue writes buf0

  // in-wave butterfly over the 4 k-split groups (lane xor 16, 32)
#pragma unroll
  for (int j = 0; j < 4; ++j) {
    aR[j] += __shfl_xor(aR[j], 16); aR[j] += __shfl_xor(aR[j], 32);
    aZ[j] += __shfl_xor(aZ[j], 16); aZ[j] += __shfl_xor(aZ[j], 32);
    aX[j] += __shfl_xor(aX[j], 16); aX[j] += __shfl_xor(aX[j], 32);
    aN[j] += __shfl_xor(aN[j], 16); aN[j] += __shfl_xor(aN[j], 32);
  }

  // distributed epilogue: lane (hc, ks) finishes row rb+ks, col hid (static select)
  {
    const float sR = (ks & 2) ? ((ks & 1) ? aR[3] : aR[2]) : ((ks & 1) ? aR[1] : aR[0]);
    const float sZ = (ks & 2) ? ((ks & 1) ? aZ[3] : aZ[2]) : ((ks & 1) ? aZ[1] : aZ[0]);
    const float sX = (ks & 2) ? ((ks & 1) ? aX[3] : aX[2]) : ((ks & 1) ? aX[1] : aX[0]);
    const float sN = (ks & 2) ? ((ks & 1) ? aN[3] : aN[2]) : ((ks & 1) ? aN[1] : aN[0]);
    const int hid = (g << 4) + hc;
    const int row = rb + ks;
    const float r = sigm(sR + bi[hid] + bh[hid]);
    const float z = sigm(sZ + bi[512 + hid] + bh[512 + hid]);
    const float n = tanhx(sX + bi[1024 + hid] + r * (sN + bh[1024 + hid]));
    const float hp = hprev[(size_t)(b0 + row) * H_ + hid];
    hout[(size_t)(b0 + row) * H_ + hid] = (1.f - z) * n + z * hp;
  }
}

// ---------------- the persistent kernel ----------------
__global__ __launch_bounds__(NTHR, 1) void k_main(
    float* __restrict__ ws, const float* __restrict__ x_cv, const float* __restrict__ x_tgt,
    const float* __restrict__ e_bi0, const float* __restrict__ e_bh0,
    const float* __restrict__ e_bi1, const float* __restrict__ e_bh1,
    const float* __restrict__ d_bi0, const float* __restrict__ d_bh0,
    const float* __restrict__ d_bi1, const float* __restrict__ d_bh1,
    const float* __restrict__ fc1_b, const float* __restrict__ fc2_W, const float* __restrict__ fc2_b,
    const float* __restrict__ he1_b, const float* __restrict__ he2_W, const float* __restrict__ he2_b,
    float* __restrict__ out) {
  __shared__ __align__(16) float s_act[2 * ACT_F]; // double-buffered [row][68]
  __shared__ __align__(16) float s_w[2 * W_F];     // double-buffered [gatecol][68]
  __shared__ __align__(16) float s_pv[256];        // [32 rows][8] pv values
  __shared__ __align__(16) float s_sb[32 * 132];   // head staging + H1 reduce

  const int tid = threadIdx.x;
  const int wg = blockIdx.x;
  const int ji = wg & 31;            // 0..31 hidden group
  const int bi = wg >> 5;            // 0..7 batch group
  const int b0 = bi << 5;            // 32 rows per group

  unsigned* bar = (unsigned*)ws;
  float* xemb = ws + OF_XEMB;
  float* hA[2] = {ws + OF_HA, ws + OF_HA + 131072};
  float* hB[2] = {ws + OF_HB, ws + OF_HB + 131072};
  float* pvst = ws + OF_PV;
  float* s1g = ws + OF_S1;
  float* s2g = ws + OF_S2;
  const float* wE0I = ws + OF_E0I; const float* wE0H = ws + OF_E0H;
  const float* wE1I = ws + OF_E1I; const float* wE1H = ws + OF_E1H;
  const float* wD0I = ws + OF_D0I; const float* wD0H = ws + OF_D0H;
  const float* wD1I = ws + OF_D1I; const float* wD1H = ws + OF_D1H;
  const float* wFH  = ws + OF_FH;

  // ======== encoder: L0 and L1 pipelined (L1 lags one step) ========
  for (int s = 0; s <= TE_; ++s) {
    if (s < TE_)
      gru_tile<0, KE0_>(x_cv, xemb, s, wE0I, wE0H, e_bi0, e_bh0,
                        hA[(s + 1) & 1], hA[s & 1], b0, ji, s_act, s_w, s_sb, nullptr);
    if (s >= 1)
      gru_tile<1, 512>(hA[(s + 1) & 1], nullptr, 0, wE1I, wE1H, e_bi1, e_bh1,
                       hB[s & 1], hB[(s + 1) & 1], b0, ji, s_act, s_w, s_sb, nullptr);
    bar_sync_bi(bar, bi);
  }
  // h1_fin in hA[1], h2_fin in hB[1]

  // ======== decoder ========
  for (int t = 0; t <= T_; ++t) {
    // ---- heads of step t-1 (pv feedback + outputs), or pv_init at t==0 ----
    if (t == 0) {
      if (tid < 256) s_pv[tid] = pvst[(b0 << 3) + tid];
      __syncthreads();
    } else {
      { // stage s1 rows for this b-group
        int row = tid >> 4, co = (tid & 15) << 3;
        float4 v0 = *(const float4*)(s1g + (size_t)(b0 + row) * 128 + co);
        float4 v1 = *(const float4*)(s1g + (size_t)(b0 + row) * 128 + co + 4);
        *(float4*)(s_sb + row * 132 + co) = v0;
        *(float4*)(s_sb + row * 132 + co + 4) = v1;
      }
      __syncthreads();
      if (tid < 160) { // pv = s1 @ fc2^T + b  (redundant per WG; needed for pv feedback)
        int bl2 = tid & 31, p = tid >> 5;
        float acc = fc2_b[p];
        const float4* sb4 = (const float4*)(s_sb + bl2 * 132);
        const float4* w4 = (const float4*)(fc2_W + p * 128);
#pragma unroll 8
        for (int c = 0; c < 32; ++c) {
          float4 a = sb4[c], w = w4[c];
          acc = fmaf(a.x, w.x, acc); acc = fmaf(a.y, w.y, acc);
          acc = fmaf(a.z, w.z, acc); acc = fmaf(a.w, w.w, acc);
        }
        s_pv[(bl2 << 3) + p] = acc;
      }
      __syncthreads();
      if (ji == 1 && tid < 160) { // one WG per b-group writes pv output
        int bl2 = tid & 31, p = tid >> 5;
        out[((size_t)(b0 + bl2) * T_ + (t - 1)) * 5 + p] = s_pv[(bl2 << 3) + p];
      }
      if (ji == 0) { // one WG per b-group computes + writes he output
        int row = tid >> 4, co = (tid & 15) << 3;
        float4 v0 = *(const float4*)(s2g + (size_t)(b0 + row) * 128 + co);
        float4 v1 = *(const float4*)(s2g + (size_t)(b0 + row) * 128 + co + 4);
        *(float4*)(s_sb + row * 132 + co) = v0;
        *(float4*)(s_sb + row * 132 + co + 4) = v1;
        __syncthreads();
        int bl2 = tid & 31, e = tid >> 5;
        float acc = he2_b[e];
        const float4* sb4 = (const float4*)(s_sb + bl2 * 132);
        const float4* w4 = (const float4*)(he2_W + e * 128);
#pragma unroll 8
        for (int c = 0; c < 32; ++c) {
          float4 a = sb4[c], w = w4[c];
          acc = fmaf(a.x, w.x, acc); acc = fmaf(a.y, w.y, acc);
          acc = fmaf(a.z, w.z, acc); acc = fmaf(a.w, w.w, acc);
        }
        out[OUT_HE_OFS + ((size_t)(b0 + bl2) * T_ + (t - 1)) * 16 + e] = acc;
      }
    }

    if (t < T_) {
      // ---- phase D0: d1_t ----
      gru_tile<2, KD0_>(x_tgt, nullptr, t, wD0I, wD0H, d_bi0, d_bh0,
                        hA[(t + 1) & 1], hA[t & 1], b0, ji, s_act, s_w, s_sb, s_pv);
      bar_sync_bi(bar, bi);
      // ---- phase D1: d2_t ----
      gru_tile<1, 512>(hA[t & 1], nullptr, 0, wD1I, wD1H, d_bi1, d_bh1,
                       hB[(t + 1) & 1], hB[t & 1], b0, ji, s_act, s_w, s_sb, nullptr);
      bar_sync_bi(bar, bi);
      // ---- phase H1: s1 = relu(d2@fc1^T + b), s2 = relu(d2@he1^T + b) ----
      // double-buffered: one sync per 64-k step
      {
        const float* d2 = hB[t & 1];
        const int c = tid & 7;               // output col 0..7 (4 fc1 + 4 he1)
        const int rp2 = (tid >> 3) & 15;     // row pair
        const int ks2 = tid >> 7;            // 4-way k split
        const int r0h = rp2 << 1, r1h = r0h + 1;
        float aF0 = 0.f, aF1 = 0.f;
        float4 wv = {0,0,0,0}, av;
        // prologue: tile 0 regs -> buf0
        if (tid < 128)
          wv = *(const float4*)(wFH + (size_t)((ji << 3) + (tid >> 4)) * 512 + ((tid & 15) << 2));
        av = *(const float4*)(d2 + (size_t)(b0 + (tid >> 4)) * H_ + ((tid & 15) << 2));
        {
          float4* W4 = (float4*)s_w;
          float4* A4 = (float4*)s_act;
          if (tid < 128) W4[(tid >> 4) * 17 + (tid & 15)] = wv;
          A4[(tid >> 4) * 17 + (tid & 15)] = av;
        }
        for (int kt = 0; kt < 8; ++kt) {
          const int cur = kt & 1;
          __syncthreads();
          if (kt + 1 < 8) {
            const int k0 = (kt + 1) << 6;
            if (tid < 128)
              wv = *(const float4*)(wFH + (size_t)((ji << 3) + (tid >> 4)) * 512 + k0 + ((tid & 15) << 2));
            av = *(const float4*)(d2 + (size_t)(b0 + (tid >> 4)) * H_ + k0 + ((tid & 15) << 2));
          }
          const float4* A4c = (const float4*)(s_act + cur * ACT_F);
          const float4* W4c = (const float4*)(s_w + cur * W_F);
          const int qb = ks2 << 2;
#pragma unroll 2
          for (int ch = 0; ch < 4; ++ch) {
            const int q_ = qb + ch;
            const float4 a0 = A4c[r0h * 17 + q_];
            const float4 a1 = A4c[r1h * 17 + q_];
            const float4 w = W4c[c * 17 + q_];
            aF0 = fmaf(a0.x, w.x, aF0); aF0 = fmaf(a0.y, w.y, aF0);
            aF0 = fmaf(a0.z, w.z, aF0); aF0 = fmaf(a0.w, w.w, aF0);
            aF1 = fmaf(a1.x, w.x, aF1); aF1 = fmaf(a1.y, w.y, aF1);
            aF1 = fmaf(a1.z, w.z, aF1); aF1 = fmaf(a1.w, w.w, aF1);
          }
          if (kt + 1 < 8) {
            float4* W4 = (float4*)(s_w + (cur ^ 1) * W_F);
            float4* A4 = (float4*)(s_act + (cur ^ 1) * ACT_F);
            if (tid < 128) W4[(tid >> 4) * 17 + (tid & 15)] = wv;
            A4[(tid >> 4) * 17 + (tid & 15)] = av;
          }
        }
        if (ks2) {
          float* rbf = s_sb + (size_t)(tid & 127) * 9 + ((ks2 - 1) << 1);
          rbf[0] = aF0; rbf[1] = aF1;
        }
        __syncthreads();
        if (tid < 128) {
          const float* rbf = s_sb + (size_t)tid * 9;
          aF0 += rbf[0] + rbf[2] + rbf[4];
          aF1 += rbf[1] + rbf[3] + rbf[5];
          if (c < 4) {
            const float bb = fc1_b[(ji << 2) + c];
            s1g[(size_t)(b0 + r0h) * 128 + (ji << 2) + c] = fmaxf(aF0 + bb, 0.f);
            s1g[(size_t)(b0 + r1h) * 128 + (ji << 2) + c] = fmaxf(aF1 + bb, 0.f);
          } else {
            const float bb = he1_b[(ji << 2) + c - 4];
            s2g[(size_t)(b0 + r0h) * 128 + (ji << 2) + c - 4] = fmaxf(aF0 + bb, 0.f);
            s2g[(size_t)(b0 + r1h) * 128 + (ji << 2) + c - 4] = fmaxf(aF1 + bb, 0.f);
          }
        }
      }
      bar_sync_bi(bar, bi);
    }
  }
}

// ---------------- host ----------------
extern "C" void kernel_launch(void* const* d_in, const int* in_sizes, int n_in,
                              void* d_out, int out_size, void* d_ws, size_t ws_size,
                              hipStream_t stream) {
  float* ws = (float*)d_ws;
  const float* x_cv   = (const float*)d_in[0];
  const float* x_tgt  = (const float*)d_in[1];
  const float* pv_init= (const float*)d_in[2];
  const int*   scen   = (const int*)d_in[3];
  const float* emb    = (const float*)d_in[4];
  const float* eWih0  = (const float*)d_in[5];
  const float* eWhh0  = (const float*)d_in[6];
  const float* ebi0   = (const float*)d_in[7];
  const float* ebh0   = (const float*)d_in[8];
  const float* eWih1  = (const float*)d_in[9];
  const float* eWhh1  = (const float*)d_in[10];
  const float* ebi1   = (const float*)d_in[11];
  const float* ebh1   = (const float*)d_in[12];
  const float* dWih0  = (const float*)d_in[13];
  const float* dWhh0  = (const float*)d_in[14];
  const float* dbi0   = (const float*)d_in[15];
  const float* dbh0   = (const float*)d_in[16];
  const float* dWih1  = (const float*)d_in[17];
  const float* dWhh1  = (const float*)d_in[18];
  const float* dbi1   = (const float*)d_in[19];
  const float* dbh1   = (const float*)d_in[20];
  const float* fc1W   = (const float*)d_in[21];
  const float* fc1b   = (const float*)d_in[22];
  const float* fc2W   = (const float*)d_in[23];
  const float* fc2b   = (const float*)d_in[24];
  const float* he1W   = (const float*)d_in[25];
  const float* he1b   = (const float*)d_in[26];
  const float* he2W   = (const float*)d_in[27];
  const float* he2b   = (const float*)d_in[28];

  hipLaunchKernelGGL(k_init, dim3(512), dim3(256), 0, stream, ws, pv_init, scen, emb);
  hipLaunchKernelGGL(k_rearr, dim3(512), dim3(256), 0, stream, ws + OF_E0I, eWih0, 160, 160);
  hipLaunchKernelGGL(k_rearr, dim3(512), dim3(256), 0, stream, ws + OF_E0H, eWhh0, 512, 512);
  hipLaunchKernelGGL(k_rearr, dim3(512), dim3(256), 0, stream, ws + OF_E1I, eWih1, 512, 512);
  hipLaunchKernelGGL(k_rearr, dim3(512), dim3(256), 0, stream, ws + OF_E1H, eWhh1, 512, 512);
  hipLaunchKernelGGL(k_rearr, dim3(512), dim3(256), 0, stream, ws + OF_D0I, dWih0, 133, 136);
  hipLaunchKernelGGL(k_rearr, dim3(512), dim3(256), 0, stream, ws + OF_D0H, dWhh0, 512, 512);
  hipLaunchKernelGGL(k_rearr, dim3(512), dim3(256), 0, stream, ws + OF_D1I, dWih1, 512, 512);
  hipLaunchKernelGGL(k_rearr, dim3(512), dim3(256), 0, stream, ws + OF_D1H, dWhh1, 512, 512);
  hipLaunchKernelGGL(k_rearr_fh, dim3(256), dim3(256), 0, stream, ws + OF_FH, fc1W, he1W);

  hipLaunchKernelGGL(k_main, dim3(NBLK), dim3(NTHR), 0, stream,
                     ws, x_cv, x_tgt, ebi0, ebh0, ebi1, ebh1, dbi0, dbh0, dbi1, dbh1,
                     fc1b, fc2W, fc2b, he1b, he2W, he2b, (float*)d_out);
}

// Round 6
// 73101.129 us; speedup vs baseline: 1.0386x; 1.0386x over previous
//
#include <hip/hip_runtime.h>

#define NTHR 512
#define NBLK 256

// problem dims
#define B_    256
#define TE_   300
#define T_    600
#define NIN_  128
#define H_    512
#define EMB_  32
#define KE0_  160
#define KD0_  136            // 133 padded to 136 (zeros) for float4-aligned tiles
#define OUT_HE_OFS 768000ull // 256*600*5

// LDS tile sizes (floats)
#define ACT_F (32 * 68)
#define W_F   (48 * 68)

// ---- workspace layout (float offsets) ----
constexpr size_t OF_BAR  = 0;                       // 1024 floats (per-bi barriers)
constexpr size_t OF_XEMB = 1024;                    // 256*32
constexpr size_t OF_HA   = OF_XEMB + 8192;          // 2 * 256*512
constexpr size_t OF_HB   = OF_HA + 262144;          // 2 * 256*512
constexpr size_t OF_PV   = OF_HB + 262144;          // 256*8
constexpr size_t OF_S1   = OF_PV + 2048;            // 256*128 relu(fc1)
constexpr size_t OF_S2   = OF_S1 + 32768;           // 256*128 relu(he1)
constexpr size_t OF_E0I  = OF_S2 + 32768;           // 32*48*160
constexpr size_t OF_E0H  = OF_E0I + 245760;         // 32*48*512
constexpr size_t OF_E1I  = OF_E0H + 786432;
constexpr size_t OF_E1H  = OF_E1I + 786432;
constexpr size_t OF_D0I  = OF_E1H + 786432;         // 32*48*136
constexpr size_t OF_D0H  = OF_D0I + 208896;
constexpr size_t OF_D1I  = OF_D0H + 786432;
constexpr size_t OF_D1H  = OF_D1I + 786432;
constexpr size_t OF_FH   = OF_D1H + 786432;         // 32*8*512 (fc1+he1, c-major)
constexpr size_t WS_END  = OF_FH + 131072;          // ~23.6 MB total

// ---------------- init: zero barrier, build xemb, pv state, zero h slot-1 ----------------
__global__ void k_init(float* __restrict__ ws, const float* __restrict__ pv_init,
                       const int* __restrict__ scen, const float* __restrict__ emb) {
  const size_t total = 1024 + 8192 + 2048 + 131072 + 131072;
  size_t stride = (size_t)gridDim.x * blockDim.x;
  for (size_t x = (size_t)blockIdx.x * blockDim.x + threadIdx.x; x < total; x += stride) {
    if (x < 1024) {
      ((unsigned*)ws)[x] = 0u;
    } else if (x < 1024 + 8192) {
      size_t r = x - 1024; int b = (int)(r >> 5), e = (int)(r & 31);
      ws[OF_XEMB + r] = emb[scen[b] * EMB_ + e];
    } else if (x < 1024 + 8192 + 2048) {
      size_t r = x - 1024 - 8192; int b = (int)(r >> 3), p = (int)(r & 7);
      ws[OF_PV + r] = (p < 5) ? pv_init[b * 5 + p] : 0.f;
    } else if (x < 1024 + 8192 + 2048 + 131072) {
      ws[OF_HA + 131072 + (x - 1024 - 8192 - 2048)] = 0.f;        // hA slot 1 = zeros
    } else {
      ws[OF_HB + 131072 + (x - 1024 - 8192 - 2048 - 131072)] = 0.f; // hB slot 1 = zeros
    }
  }
}

// ---------------- weight rearrange: dst[g][c][Kp], c = gate*16 + hid_local ----------------
// c-major rows of padded length Kp (zeros for k>=K) so LDS staging/readers use float4.
__global__ void k_rearr(float* __restrict__ dst, const float* __restrict__ src, int K, int Kp) {
  int n = 32 * 48 * Kp;
  for (int idx = blockIdx.x * blockDim.x + threadIdx.x; idx < n; idx += gridDim.x * blockDim.x) {
    int g = idx / (48 * Kp), r = idx % (48 * Kp), c = r / Kp, k = r % Kp;
    int j = (c >> 4) * 512 + g * 16 + (c & 15);
    dst[idx] = (k < K) ? src[j * K + k] : 0.f;
  }
}
// fc1/he1 combined, c-major: dst[g][c][512] (c<4: fc1 col g*4+c; c>=4: he1 col g*4+c-4)
__global__ void k_rearr_fh(float* __restrict__ dst, const float* __restrict__ fc1,
                           const float* __restrict__ he1) {
  int n = 32 * 8 * 512;
  for (int idx = blockIdx.x * blockDim.x + threadIdx.x; idx < n; idx += gridDim.x * blockDim.x) {
    int g = idx / (8 * 512), r = idx % (8 * 512), c = r / 512, k = r % 512;
    const float* s = (c < 4) ? fc1 : he1;
    dst[idx] = s[(g * 4 + (c & 3)) * 512 + k];
  }
}

// ---------------- device helpers ----------------
__device__ __forceinline__ float sigm(float x) { return 1.f / (1.f + __expf(-x)); }
__device__ __forceinline__ float tanhx(float x) { float e = __expf(2.f * x); return 1.f - 2.f / (e + 1.f); }

// per-bi-group barrier: 32 WGs sharing batch rows sync; groups are independent
// (hA/hB/s1g/s2g/pv are row-partitioned; weights read-only).
__device__ __forceinline__ void bar_sync_bi(unsigned* bar, int big) {
  __syncthreads();
  if (threadIdx.x == 0) {
    unsigned* cnt = &bar[big << 6];
    unsigned* gen = &bar[(big << 6) + 16];
    unsigned g0 = __hip_atomic_load(gen, __ATOMIC_RELAXED, __HIP_MEMORY_SCOPE_AGENT);
    unsigned n = __hip_atomic_fetch_add(cnt, 1u, __ATOMIC_ACQ_REL, __HIP_MEMORY_SCOPE_AGENT);
    if (n == 31u) {
      __hip_atomic_store(cnt, 0u, __ATOMIC_RELAXED, __HIP_MEMORY_SCOPE_AGENT);
      __hip_atomic_store(gen, g0 + 1u, __ATOMIC_RELEASE, __HIP_MEMORY_SCOPE_AGENT);
    } else {
      while (__hip_atomic_load(gen, __ATOMIC_ACQUIRE, __HIP_MEMORY_SCOPE_AGENT) == g0)
        __builtin_amdgcn_s_sleep(1);
    }
  }
  __syncthreads();
}

#define FMA4(ACC, AV, WV)                                   \
  ACC = fmaf(AV.x, WV.x, ACC); ACC = fmaf(AV.y, WV.y, ACC); \
  ACC = fmaf(AV.z, WV.z, ACC); ACC = fmaf(AV.w, WV.w, ACC);

// one 4-k chunk, 4 rows: 7 ds_read_b128 -> 48 FMAs (4 rows x 3 gates x 4 k).
// Within a wave: q_ is uniform (ks wave-uniform), W addrs vary only by hc (16 distinct,
// 2-way bank alias = free), A addrs vary only by rq (broadcast) -> conflict-free.
#define GQ4(Q, AX)                                                                   \
  { const int q_ = (Q);                                                              \
    const float4 wr = W4c[hc * 17 + q_];                                             \
    const float4 wz = W4c[(16 + hc) * 17 + q_];                                      \
    const float4 wn = W4c[(32 + hc) * 17 + q_];                                      \
    const float4 a0 = A4c[(rb + 0) * 17 + q_];                                       \
    const float4 a1 = A4c[(rb + 1) * 17 + q_];                                       \
    const float4 a2 = A4c[(rb + 2) * 17 + q_];                                       \
    const float4 a3 = A4c[(rb + 3) * 17 + q_];                                       \
    FMA4(aR[0], a0, wr) FMA4(aR[1], a1, wr) FMA4(aR[2], a2, wr) FMA4(aR[3], a3, wr)  \
    FMA4(aZ[0], a0, wz) FMA4(aZ[1], a1, wz) FMA4(aZ[2], a2, wz) FMA4(aZ[3], a3, wz)  \
    FMA4(AX[0], a0, wn) FMA4(AX[1], a1, wn) FMA4(AX[2], a2, wn) FMA4(AX[3], a3, wn)  \
  }

// register prefetch of one 64-k tile's operands (global -> VGPR)
template <int KIND, int KI>
__device__ __forceinline__ void stage_pref(
    int kt, int tid, int b0, int g, int t,
    const float* __restrict__ actA, const float* __restrict__ actB,
    const float* __restrict__ wi, const float* __restrict__ wh,
    const float* __restrict__ hprev,
    float4& wv0, float4& wv1, float4& av, bool& w0v, bool& w1v, bool& a_v) {
  constexpr int NTI = (KI + 63) >> 6;
  w0v = false; w1v = false; a_v = false;
  if (kt < NTI) {
    const int k0 = kt << 6;
    const int cnt = (KI - k0 >= 64) ? 64 : (KI - k0);
    const int L = (cnt == 64) ? 4 : (cnt == 32) ? 3 : 1;
    const int M = (1 << L) - 1;
    if (tid < (48 << L)) {
      w0v = true;
      const int c0 = tid >> L, f0 = tid & M;
      wv0 = *(const float4*)(wi + (size_t)(g * 48 + c0) * KI + k0 + (f0 << 2));
    }
    const int i1 = tid + 512;
    if (i1 < (48 << L)) {
      w1v = true;
      const int c1 = i1 >> L, f1 = i1 & M;
      wv1 = *(const float4*)(wi + (size_t)(g * 48 + c1) * KI + k0 + (f1 << 2));
    }
    if (tid < (32 << L)) {
      const int row = tid >> L, f = tid & M;
      if (KIND == 1) {
        av = *(const float4*)(actA + (size_t)(b0 + row) * H_ + k0 + (f << 2)); a_v = true;
      } else if (KIND == 0) {
        if (k0 < 128) {
          av = *(const float4*)(actA + ((size_t)(b0 + row) * TE_ + t) * NIN_ + k0 + (f << 2)); a_v = true;
        } else {
          av = *(const float4*)(actB + (size_t)(b0 + row) * EMB_ + (f << 2)); a_v = true;
        }
      } else {
        if (k0 < 128) {
          av = *(const float4*)(actA + ((size_t)(b0 + row) * T_ + t) * NIN_ + k0 + (f << 2)); a_v = true;
        } // pv tail filled from s_pvl at store time
      }
    }
  } else {
    const int k0 = (kt - NTI) << 6;
    w0v = true;
    wv0 = *(const float4*)(wh + (size_t)(g * 48 + (tid >> 4)) * 512 + k0 + ((tid & 15) << 2));
    if (tid < 256) {
      w1v = true;
      wv1 = *(const float4*)(wh + (size_t)(g * 48 + 32 + (tid >> 4)) * 512 + k0 + ((tid & 15) << 2));
    }
    av = *(const float4*)(hprev + (size_t)(b0 + (tid >> 4)) * H_ + k0 + ((tid & 15) << 2));
    a_v = true;
  }
}

// regs -> LDS for tile kt into the given half of the double buffer
template <int KIND, int KI>
__device__ __forceinline__ void stage_write(
    int kt, int tid, float* __restrict__ s_act_b, float* __restrict__ s_w_b,
    const float4& wv0, const float4& wv1, const float4& av,
    bool w0v, bool w1v, bool a_v, const float* __restrict__ s_pvl) {
  constexpr int NTI = (KI + 63) >> 6;
  const bool is_input = (kt < NTI);
  const int k0i = kt << 6;
  const int cnt = is_input ? ((KI - k0i >= 64) ? 64 : (KI - k0i)) : 64;
  const int L = (cnt == 64) ? 4 : (cnt == 32) ? 3 : 1;
  const int M = (1 << L) - 1;
  float4* W4 = (float4*)s_w_b;
  float4* A4 = (float4*)s_act_b;
  if (w0v) W4[(tid >> L) * 17 + (tid & M)] = wv0;
  if (w1v) { const int i1 = tid + 512; W4[(i1 >> L) * 17 + (i1 & M)] = wv1; }
  if (a_v) A4[(tid >> L) * 17 + (tid & M)] = av;
  if (KIND == 2 && is_input && k0i == 128 && tid < 64) {
    const int row = tid >> 1, f = tid & 1;
    float4 v;
    if (f == 0) {
      v.x = s_pvl[(row << 3) + 0]; v.y = s_pvl[(row << 3) + 1];
      v.z = s_pvl[(row << 3) + 2]; v.w = s_pvl[(row << 3) + 3];
    } else {
      v.x = s_pvl[(row << 3) + 4]; v.y = 0.f; v.z = 0.f; v.w = 0.f;
    }
    A4[row * 17 + f] = v;
  }
}

// One GRU step for this WG's tile: 32 batch rows x 16 hidden cols.
// Thread = (hc: bits 0-3, rq: bits 4-6 row-quad, ks: bits 7-8 k-quarter; ks WAVE-UNIFORM).
// Per thread: 4 rows x 16 k -> 7 ds_read_b128 per 48 FMAs, broadcast-friendly banks.
// Split-k combined by a 2-round field-major LDS tree (once per GRU step).
// LDS: act[row][68], w[gatecol][68], double-buffered -> ONE sync per 64-k tile.
// KIND 0: enc L0 (x_cv ++ xemb), 1: plain H input, 2: dec L0 (x_tgt ++ pv from s_pvl)
template <int KIND, int KI>
__device__ void gru_tile(const float* __restrict__ actA, const float* __restrict__ actB, int t,
                         const float* __restrict__ wi, const float* __restrict__ wh,
                         const float* __restrict__ bi, const float* __restrict__ bh,
                         const float* __restrict__ hprev, float* __restrict__ hout,
                         int b0, int g, float* __restrict__ s_act, float* __restrict__ s_w,
                         float* __restrict__ s_sb, const float* __restrict__ s_pvl) {
  const int tid = threadIdx.x;
  const int hc = tid & 15;            // hidden col 0..15
  const int rq = (tid >> 4) & 7;      // row quad 0..7
  const int ks = tid >> 7;            // k quarter 0..3 (wave-uniform: wave=tid>>6, ks=wave>>1)
  const int rb = rq << 2;             // first of this thread's 4 rows
  float aR[4] = {0.f,0.f,0.f,0.f}, aZ[4] = {0.f,0.f,0.f,0.f};
  float aX[4] = {0.f,0.f,0.f,0.f}, aN[4] = {0.f,0.f,0.f,0.f};
  constexpr int NTI = (KI + 63) >> 6;
  constexpr int NTT = NTI + 8;

  float4 wv0 = {0,0,0,0}, wv1 = {0,0,0,0}, av = {0,0,0,0};
  bool w0v = false, w1v = false, a_v = false;
  // prologue: tile 0 -> buf0 (prior phase's LDS reads are behind its trailing syncs)
  stage_pref<KIND, KI>(0, tid, b0, g, t, actA, actB, wi, wh, hprev, wv0, wv1, av, w0v, w1v, a_v);
  stage_write<KIND, KI>(0, tid, s_act, s_w, wv0, wv1, av, w0v, w1v, a_v, s_pvl);

  for (int kt = 0; kt < NTT; ++kt) {
    const bool is_input = (kt < NTI);
    const int k0i = kt << 6;
    const int cnt = is_input ? ((KI - k0i >= 64) ? 64 : (KI - k0i)) : 64;
    const int cur = kt & 1;

    __syncthreads();   // tile kt's writes visible; buf[cur^1] readers (tile kt-1) done
    if (kt + 1 < NTT)
      stage_pref<KIND, KI>(kt + 1, tid, b0, g, t, actA, actB, wi, wh, hprev, wv0, wv1, av, w0v, w1v, a_v);

    const float4* A4c = (const float4*)(s_act + cur * ACT_F);
    const float4* W4c = (const float4*)(s_w + cur * W_F);
    if (is_input) {
      if (cnt == 64) {
        const int qb = ks << 2;
#pragma unroll 2
        for (int ch = 0; ch < 4; ++ch) GQ4(qb + ch, aX)
      } else if (cnt == 32) {
        const int qb = ks << 1;
#pragma unroll 2
        for (int ch = 0; ch < 2; ++ch) GQ4(qb + ch, aX)
      } else { // cnt == 8: 2 chunks, ks 0/1 only
        if (ks < 2) GQ4(ks, aX)
      }
    } else {
      const int qb = ks << 2;
#pragma unroll 2
      for (int ch = 0; ch < 4; ++ch) GQ4(qb + ch, aN)
    }

    if (kt + 1 < NTT)
      stage_write<KIND, KI>(kt + 1, tid, s_act + (cur ^ 1) * ACT_F, s_w + (cur ^ 1) * W_F,
                            wv0, wv1, av, w0v, w1v, a_v, s_pvl);
  }

  // ---- 4-way split-k tree reduce (field-major, conflict-free lanes) ----
  float4* sb4 = (float4*)s_sb;        // uses 1024 float4 = 4096 floats of s_sb
  __syncthreads();                    // all compute reads of s_act/s_w done
  if (ks >= 2) {                      // round A write: ks=2,3 -> slots [field][ (ks-2)*128 + idx ]
    const int idx = ((ks - 2) << 7) | (tid & 127);
    sb4[          idx] = make_float4(aR[0], aR[1], aR[2], aR[3]);
    sb4[256  +    idx] = make_float4(aZ[0], aZ[1], aZ[2], aZ[3]);
    sb4[512  +    idx] = make_float4(aX[0], aX[1], aX[2], aX[3]);
    sb4[768  +    idx] = make_float4(aN[0], aN[1], aN[2], aN[3]);
  }
  __syncthreads();
  if (ks < 2) {                       // round A combine: ks=0 += ks=2, ks=1 += ks=3
    const int idx = (ks << 7) | (tid & 127);
    const float4 vr = sb4[idx], vz = sb4[256 + idx], vx = sb4[512 + idx], vn = sb4[768 + idx];
    aR[0] += vr.x; aR[1] += vr.y; aR[2] += vr.z; aR[3] += vr.w;
    aZ[0] += vz.x; aZ[1] += vz.y; aZ[2] += vz.z; aZ[3] += vz.w;
    aX[0] += vx.x; aX[1] += vx.y; aX[2] += vx.z; aX[3] += vx.w;
    aN[0] += vn.x; aN[1] += vn.y; aN[2] += vn.z; aN[3] += vn.w;
  }
  __syncthreads();
  if (ks == 1) {                      // round B write
    const int idx = tid & 127;
    sb4[          idx] = make_float4(aR[0], aR[1], aR[2], aR[3]);
    sb4[256  +    idx] = make_float4(aZ[0], aZ[1], aZ[2], aZ[3]);
    sb4[512  +    idx] = make_float4(aX[0], aX[1], aX[2], aX[3]);
    sb4[768  +    idx] = make_float4(aN[0], aN[1], aN[2], aN[3]);
  }
  __syncthreads();
  if (ks == 0) {                      // round B combine + epilogue (4 rows per thread)
    const int idx = tid;
    const float4 vr = sb4[idx], vz = sb4[256 + idx], vx = sb4[512 + idx], vn = sb4[768 + idx];
    aR[0] += vr.x; aR[1] += vr.y; aR[2] += vr.z; aR[3] += vr.w;
    aZ[0] += vz.x; aZ[1] += vz.y; aZ[2] += vz.z; aZ[3] += vz.w;
    aX[0] += vx.x; aX[1] += vx.y; aX[2] += vx.z; aX[3] += vx.w;
    aN[0] += vn.x; aN[1] += vn.y; aN[2] += vn.z; aN[3] += vn.w;
    const int hid = (g << 4) + hc;
    const float biR = bi[hid] + bh[hid];
    const float biZ = bi[512 + hid] + bh[512 + hid];
    const float biN = bi[1024 + hid], bhN = bh[1024 + hid];
#pragma unroll
    for (int j = 0; j < 4; ++j) {
      const float r = sigm(aR[j] + biR), z = sigm(aZ[j] + biZ);
      const float n = tanhx(aX[j] + biN + r * (aN[j] + bhN));
      const float hp = hprev[(size_t)(b0 + rb + j) * H_ + hid];
      hout[(size_t)(b0 + rb + j) * H_ + hid] = (1.f - z) * n + z * hp;
    }
  }
}

// ---------------- the persistent kernel ----------------
__global__ __launch_bounds__(NTHR, 1) void k_main(
    float* __restrict__ ws, const float* __restrict__ x_cv, const float* __restrict__ x_tgt,
    const float* __restrict__ e_bi0, const float* __restrict__ e_bh0,
    const float* __restrict__ e_bi1, const float* __restrict__ e_bh1,
    const float* __restrict__ d_bi0, const float* __restrict__ d_bh0,
    const float* __restrict__ d_bi1, const float* __restrict__ d_bh1,
    const float* __restrict__ fc1_b, const float* __restrict__ fc2_W, const float* __restrict__ fc2_b,
    const float* __restrict__ he1_b, const float* __restrict__ he2_W, const float* __restrict__ he2_b,
    float* __restrict__ out) {
  __shared__ __align__(16) float s_act[2 * ACT_F]; // double-buffered [row][68]
  __shared__ __align__(16) float s_w[2 * W_F];     // double-buffered [gatecol][68]
  __shared__ __align__(16) float s_pv[256];        // [32 rows][8] pv values
  __shared__ __align__(16) float s_sb[32 * 132];   // head staging + split-k reduce

  const int tid = threadIdx.x;
  const int wg = blockIdx.x;
  const int ji = wg & 31;            // 0..31 hidden group
  const int bi = wg >> 5;            // 0..7 batch group
  const int b0 = bi << 5;            // 32 rows per group

  unsigned* bar = (unsigned*)ws;
  float* xemb = ws + OF_XEMB;
  float* hA[2] = {ws + OF_HA, ws + OF_HA + 131072};
  float* hB[2] = {ws + OF_HB, ws + OF_HB + 131072};
  float* pvst = ws + OF_PV;
  float* s1g = ws + OF_S1;
  float* s2g = ws + OF_S2;
  const float* wE0I = ws + OF_E0I; const float* wE0H = ws + OF_E0H;
  const float* wE1I = ws + OF_E1I; const float* wE1H = ws + OF_E1H;
  const float* wD0I = ws + OF_D0I; const float* wD0H = ws + OF_D0H;
  const float* wD1I = ws + OF_D1I; const float* wD1H = ws + OF_D1H;
  const float* wFH  = ws + OF_FH;

  // ======== encoder: L0 and L1 pipelined (L1 lags one step) ========
  for (int s = 0; s <= TE_; ++s) {
    if (s < TE_)
      gru_tile<0, KE0_>(x_cv, xemb, s, wE0I, wE0H, e_bi0, e_bh0,
                        hA[(s + 1) & 1], hA[s & 1], b0, ji, s_act, s_w, s_sb, nullptr);
    if (s >= 1)
      gru_tile<1, 512>(hA[(s + 1) & 1], nullptr, 0, wE1I, wE1H, e_bi1, e_bh1,
                       hB[s & 1], hB[(s + 1) & 1], b0, ji, s_act, s_w, s_sb, nullptr);
    bar_sync_bi(bar, bi);
  }
  // h1_fin in hA[1], h2_fin in hB[1]

  // ======== decoder ========
  for (int t = 0; t <= T_; ++t) {
    // ---- heads of step t-1 (pv feedback + outputs), or pv_init at t==0 ----
    if (t == 0) {
      if (tid < 256) s_pv[tid] = pvst[(b0 << 3) + tid];
      __syncthreads();
    } else {
      { // stage s1 rows for this b-group
        int row = tid >> 4, co = (tid & 15) << 3;
        float4 v0 = *(const float4*)(s1g + (size_t)(b0 + row) * 128 + co);
        float4 v1 = *(const float4*)(s1g + (size_t)(b0 + row) * 128 + co + 4);
        *(float4*)(s_sb + row * 132 + co) = v0;
        *(float4*)(s_sb + row * 132 + co + 4) = v1;
      }
      __syncthreads();
      if (tid < 160) { // pv = s1 @ fc2^T + b  (redundant per WG; needed for pv feedback)
        int bl2 = tid & 31, p = tid >> 5;
        float acc = fc2_b[p];
        const float4* sb4 = (const float4*)(s_sb + bl2 * 132);
        const float4* w4 = (const float4*)(fc2_W + p * 128);
#pragma unroll 8
        for (int c = 0; c < 32; ++c) {
          float4 a = sb4[c], w = w4[c];
          acc = fmaf(a.x, w.x, acc); acc = fmaf(a.y, w.y, acc);
          acc = fmaf(a.z, w.z, acc); acc = fmaf(a.w, w.w, acc);
        }
        s_pv[(bl2 << 3) + p] = acc;
      }
      __syncthreads();
      if (ji == 1 && tid < 160) { // one WG per b-group writes pv output
        int bl2 = tid & 31, p = tid >> 5;
        out[((size_t)(b0 + bl2) * T_ + (t - 1)) * 5 + p] = s_pv[(bl2 << 3) + p];
      }
      if (ji == 0) { // one WG per b-group computes + writes he output
        int row = tid >> 4, co = (tid & 15) << 3;
        float4 v0 = *(const float4*)(s2g + (size_t)(b0 + row) * 128 + co);
        float4 v1 = *(const float4*)(s2g + (size_t)(b0 + row) * 128 + co + 4);
        *(float4*)(s_sb + row * 132 + co) = v0;
        *(float4*)(s_sb + row * 132 + co + 4) = v1;
        __syncthreads();
        int bl2 = tid & 31, e = tid >> 5;
        float acc = he2_b[e];
        const float4* sb4 = (const float4*)(s_sb + bl2 * 132);
        const float4* w4 = (const float4*)(he2_W + e * 128);
#pragma unroll 8
        for (int c = 0; c < 32; ++c) {
          float4 a = sb4[c], w = w4[c];
          acc = fmaf(a.x, w.x, acc); acc = fmaf(a.y, w.y, acc);
          acc = fmaf(a.z, w.z, acc); acc = fmaf(a.w, w.w, acc);
        }
        out[OUT_HE_OFS + ((size_t)(b0 + bl2) * T_ + (t - 1)) * 16 + e] = acc;
      }
    }

    if (t < T_) {
      // ---- phase D0: d1_t ----
      gru_tile<2, KD0_>(x_tgt, nullptr, t, wD0I, wD0H, d_bi0, d_bh0,
                        hA[(t + 1) & 1], hA[t & 1], b0, ji, s_act, s_w, s_sb, s_pv);
      bar_sync_bi(bar, bi);
      // ---- phase D1: d2_t ----
      gru_tile<1, 512>(hA[t & 1], nullptr, 0, wD1I, wD1H, d_bi1, d_bh1,
                       hB[(t + 1) & 1], hB[t & 1], b0, ji, s_act, s_w, s_sb, nullptr);
      bar_sync_bi(bar, bi);
      // ---- phase H1: s1 = relu(d2@fc1^T + b), s2 = relu(d2@he1^T + b) ----
      // double-buffered: one sync per 64-k step
      {
        const float* d2 = hB[t & 1];
        const int c = tid & 7;               // output col 0..7 (4 fc1 + 4 he1)
        const int rp2 = (tid >> 3) & 15;     // row pair
        const int ks2 = tid >> 7;            // 4-way k split
        const int r0h = rp2 << 1, r1h = r0h + 1;
        float aF0 = 0.f, aF1 = 0.f;
        float4 wv = {0,0,0,0}, av;
        // prologue: tile 0 regs -> buf0
        if (tid < 128)
          wv = *(const float4*)(wFH + (size_t)((ji << 3) + (tid >> 4)) * 512 + ((tid & 15) << 2));
        av = *(const float4*)(d2 + (size_t)(b0 + (tid >> 4)) * H_ + ((tid & 15) << 2));
        {
          float4* W4 = (float4*)s_w;
          float4* A4 = (float4*)s_act;
          if (tid < 128) W4[(tid >> 4) * 17 + (tid & 15)] = wv;
          A4[(tid >> 4) * 17 + (tid & 15)] = av;
        }
        for (int kt = 0; kt < 8; ++kt) {
          const int cur = kt & 1;
          __syncthreads();
          if (kt + 1 < 8) {
            const int k0 = (kt + 1) << 6;
            if (tid < 128)
              wv = *(const float4*)(wFH + (size_t)((ji << 3) + (tid >> 4)) * 512 + k0 + ((tid & 15) << 2));
            av = *(const float4*)(d2 + (size_t)(b0 + (tid >> 4)) * H_ + k0 + ((tid & 15) << 2));
          }
          const float4* A4c = (const float4*)(s_act + cur * ACT_F);
          const float4* W4c = (const float4*)(s_w + cur * W_F);
          const int qb = ks2 << 2;
#pragma unroll 2
          for (int ch = 0; ch < 4; ++ch) {
            const int q_ = qb + ch;
            const float4 a0 = A4c[r0h * 17 + q_];
            const float4 a1 = A4c[r1h * 17 + q_];
            const float4 w = W4c[c * 17 + q_];
            aF0 = fmaf(a0.x, w.x, aF0); aF0 = fmaf(a0.y, w.y, aF0);
            aF0 = fmaf(a0.z, w.z, aF0); aF0 = fmaf(a0.w, w.w, aF0);
            aF1 = fmaf(a1.x, w.x, aF1); aF1 = fmaf(a1.y, w.y, aF1);
            aF1 = fmaf(a1.z, w.z, aF1); aF1 = fmaf(a1.w, w.w, aF1);
          }
          if (kt + 1 < 8) {
            float4* W4 = (float4*)(s_w + (cur ^ 1) * W_F);
            float4* A4 = (float4*)(s_act + (cur ^ 1) * ACT_F);
            if (tid < 128) W4[(tid >> 4) * 17 + (tid & 15)] = wv;
            A4[(tid >> 4) * 17 + (tid & 15)] = av;
          }
        }
        if (ks2) {
          float* rbf = s_sb + (size_t)(tid & 127) * 9 + ((ks2 - 1) << 1);
          rbf[0] = aF0; rbf[1] = aF1;
        }
        __syncthreads();
        if (tid < 128) {
          const float* rbf = s_sb + (size_t)tid * 9;
          aF0 += rbf[0] + rbf[2] + rbf[4];
          aF1 += rbf[1] + rbf[3] + rbf[5];
          if (c < 4) {
            const float bb = fc1_b[(ji << 2) + c];
            s1g[(size_t)(b0 + r0h) * 128 + (ji << 2) + c] = fmaxf(aF0 + bb, 0.f);
            s1g[(size_t)(b0 + r1h) * 128 + (ji << 2) + c] = fmaxf(aF1 + bb, 0.f);
          } else {
            const float bb = he1_b[(ji << 2) + c - 4];
            s2g[(size_t)(b0 + r0h) * 128 + (ji << 2) + c - 4] = fmaxf(aF0 + bb, 0.f);
            s2g[(size_t)(b0 + r1h) * 128 + (ji << 2) + c - 4] = fmaxf(aF1 + bb, 0.f);
          }
        }
      }
      bar_sync_bi(bar, bi);
    }
  }
}

// ---------------- host ----------------
extern "C" void kernel_launch(void* const* d_in, const int* in_sizes, int n_in,
                              void* d_out, int out_size, void* d_ws, size_t ws_size,
                              hipStream_t stream) {
  float* ws = (float*)d_ws;
  const float* x_cv   = (const float*)d_in[0];
  const float* x_tgt  = (const float*)d_in[1];
  const float* pv_init= (const float*)d_in[2];
  const int*   scen   = (const int*)d_in[3];
  const float* emb    = (const float*)d_in[4];
  const float* eWih0  = (const float*)d_in[5];
  const float* eWhh0  = (const float*)d_in[6];
  const float* ebi0   = (const float*)d_in[7];
  const float* ebh0   = (const float*)d_in[8];
  const float* eWih1  = (const float*)d_in[9];
  const float* eWhh1  = (const float*)d_in[10];
  const float* ebi1   = (const float*)d_in[11];
  const float* ebh1   = (const float*)d_in[12];
  const float* dWih0  = (const float*)d_in[13];
  const float* dWhh0  = (const float*)d_in[14];
  const float* dbi0   = (const float*)d_in[15];
  const float* dbh0   = (const float*)d_in[16];
  const float* dWih1  = (const float*)d_in[17];
  const float* dWhh1  = (const float*)d_in[18];
  const float* dbi1   = (const float*)d_in[19];
  const float* dbh1   = (const float*)d_in[20];
  const float* fc1W   = (const float*)d_in[21];
  const float* fc1b   = (const float*)d_in[22];
  const float* fc2W   = (const float*)d_in[23];
  const float* fc2b   = (const float*)d_in[24];
  const float* he1W   = (const float*)d_in[25];
  const float* he1b   = (const float*)d_in[26];
  const float* he2W   = (const float*)d_in[27];
  const float* he2b   = (const float*)d_in[28];

  hipLaunchKernelGGL(k_init, dim3(512), dim3(256), 0, stream, ws, pv_init, scen, emb);
  hipLaunchKernelGGL(k_rearr, dim3(512), dim3(256), 0, stream, ws + OF_E0I, eWih0, 160, 160);
  hipLaunchKernelGGL(k_rearr, dim3(512), dim3(256), 0, stream, ws + OF_E0H, eWhh0, 512, 512);
  hipLaunchKernelGGL(k_rearr, dim3(512), dim3(256), 0, stream, ws + OF_E1I, eWih1, 512, 512);
  hipLaunchKernelGGL(k_rearr, dim3(512), dim3(256), 0, stream, ws + OF_E1H, eWhh1, 512, 512);
  hipLaunchKernelGGL(k_rearr, dim3(512), dim3(256), 0, stream, ws + OF_D0I, dWih0, 133, 136);
  hipLaunchKernelGGL(k_rearr, dim3(512), dim3(256), 0, stream, ws + OF_D0H, dWhh0, 512, 512);
  hipLaunchKernelGGL(k_rearr, dim3(512), dim3(256), 0, stream, ws + OF_D1I, dWih1, 512, 512);
  hipLaunchKernelGGL(k_rearr, dim3(512), dim3(256), 0, stream, ws + OF_D1H, dWhh1, 512, 512);
  hipLaunchKernelGGL(k_rearr_fh, dim3(256), dim3(256), 0, stream, ws + OF_FH, fc1W, he1W);

  hipLaunchKernelGGL(k_main, dim3(NBLK), dim3(NTHR), 0, stream,
                     ws, x_cv, x_tgt, ebi0, ebh0, ebi1, ebh1, dbi0, dbh0, dbi1, dbh1,
                     fc1b, fc2W, fc2b, he1b, he2W, he2b, (float*)d_out);
}